// Round 3
// baseline (53696.130 us; speedup 1.0000x reference)
//
#include <hip/hip_runtime.h>

#define BSZ  128
#define TLEN 256
#define NH   1024
#define SLOT (BSZ*NH)
#define NWG  256
#define LDSB 147456   // 144 KB: W0h/g0 32K | g1,g2,g3 16K ea | g4/g6 32K | g5,g7 16K ea

using bf16x8 = __attribute__((ext_vector_type(8))) short;
using f32x4  = __attribute__((ext_vector_type(4))) float;

__device__ inline short f2bf(float f){
  union {float f; unsigned u;} v; v.f = f;
  unsigned r = v.u + 0x7fffu + ((v.u >> 16) & 1u);
  return (short)(r >> 16);
}
__device__ inline float sigf(float x){ return 1.f/(1.f+__expf(-x)); }

__device__ inline void gsync(unsigned* cnt, unsigned target){
  __syncthreads();
  if (threadIdx.x == 0){
    __builtin_amdgcn_fence(__ATOMIC_RELEASE, "agent");
    __hip_atomic_fetch_add(cnt, 1u, __ATOMIC_RELAXED, __HIP_MEMORY_SCOPE_AGENT);
    while (__hip_atomic_load(cnt, __ATOMIC_RELAXED, __HIP_MEMORY_SCOPE_AGENT) < target)
      __builtin_amdgcn_s_sleep(1);
  }
  __syncthreads();
  __builtin_amdgcn_fence(__ATOMIC_ACQUIRE, "agent");
}

// Transpose-convert: D[n][k] (bf16) = S[k][n] (f32), S is K x 2048, per blockIdx.z matrix.
__global__ __launch_bounds__(256) void transpose_bf16(const float* __restrict__ src,
                                                      short* __restrict__ dst, int K){
  const size_t mat = blockIdx.z;
  const float* S = src + mat * (size_t)K * 2048;
  short* D = dst + mat * (size_t)K * 2048;
  __shared__ float tile[32][33];
  int n0 = blockIdx.x * 32;
  int k0 = blockIdx.y * 32;
  int tx = threadIdx.x & 31, ty = threadIdx.x >> 5;
  #pragma unroll
  for (int i=0;i<4;i++)
    tile[ty + i*8][tx] = S[(size_t)(k0 + ty + i*8)*2048 + n0 + tx];
  __syncthreads();
  #pragma unroll
  for (int i=0;i<4;i++){
    int n = n0 + ty + i*8;
    D[(size_t)n*K + k0 + tx] = f2bf(tile[tx][ty + i*8]);
  }
}

__global__ __launch_bounds__(256) void init_h(const float* __restrict__ h0,
                                              float* __restrict__ hF, short* __restrict__ hB){
  int i = blockIdx.x*256 + threadIdx.x;
  float v = h0[i];
  hF[i] = v; hB[i] = f2bf(v);
}

// Swizzled LDS address for chunk j (16B) of column c (col stride 2048B, 128 chunks)
#define SWZ(base, c, j) ((base) + (c)*2048 + ((((j)+(c))&127)<<4))

__global__ __launch_bounds__(256) void rnn_persistent(
    const float* __restrict__ x, const short* __restrict__ W0T,
    const short* __restrict__ WsT, float* __restrict__ F,
    short* __restrict__ Bb, float* __restrict__ out, unsigned* __restrict__ cnt)
{
  extern __shared__ char lds[];
  const int wg = blockIdx.x, tid = threadIdx.x;
  const int wv = tid>>6, lane = tid&63, m = lane&15, q = lane>>4;
  const bool grpA = ((wg>>3)&1)==0;                 // spreads both groups across XCDs
  const int r128 = ((wg>>4)<<3)|(wg&7);            // rank within group, 0..127
  const int cb8 = r128<<3, cb4 = wg<<2;

  float* s0F=F;        float* s1F=F+SLOT;   float* s2F=F+2*SLOT; float* s3F=F+3*SLOT;
  float* s4F=F+4*SLOT; float* s5F=F+5*SLOT; float* s7F=F+6*SLOT; float* hF=F+7*SLOT;
  short* s0B=Bb;         short* s1B=Bb+SLOT;   short* s2B=Bb+2*SLOT;
  short* s3B=Bb+3*SLOT;  short* s5B=Bb+4*SLOT; short* hB=Bb+5*SLOT;

  // ---- stage weight shards into LDS (once; weights survive all fences) ----
  {
    const short* src0 = grpA ? W0T : WsT;          // region 0: W0h (grpA) / g0 (grpB)
    const int Kd0 = grpA ? 2048 : 1024, sk0 = grpA ? 1024 : 0;
    for (int u=tid; u<16*128; u+=256){
      int c=u>>7, j=u&127;
      int gc = (c<8)?(cb8+c):(1024+cb8+c-8);
      *(uint4*)(lds + SWZ(0,c,j)) = *(const uint4*)(src0 + (size_t)gc*Kd0 + sk0 + j*8);
    }
    const short* src1 = WsT + ((size_t)(grpA?4:6)<<21);  // region 81920: g4 / g6
    for (int u=tid; u<16*128; u+=256){
      int c=u>>7, j=u&127;
      int gc = (c<8)?(cb8+c):(1024+cb8+c-8);
      *(uint4*)(lds + SWZ(81920,c,j)) = *(const uint4*)(src1 + (size_t)gc*1024 + j*8);
    }
    const int g8[5] = {1,2,3,5,7};
    const int b8[5] = {32768,49152,65536,114688,131072};
    for (int r=0;r<5;r++){
      const short* s = WsT + ((size_t)g8[r]<<21);
      for (int u=tid; u<8*128; u+=256){
        int c=u>>7, j=u&127;
        int gc=(c<4)?(cb4+c):(1024+cb4+c-4);
        *(uint4*)(lds + SWZ(b8[r],c,j)) = *(const uint4*)(s + (size_t)gc*1024 + j*8);
      }
    }
  }
  __syncthreads();

  const int row0 = (wv<<4) + m;       // A-row this lane reads, row-tile 0
  const int row1 = ((wv+4)<<4) + m;   // row-tile 1
  const int src8  = (lane&48)|((m+8)&15);   // partner lane: H-half, 16-col tiles
  const int src4  = (lane&48)|((m+4)&15);   // partner lane: H-half, dup tiles
  unsigned target = 0;

  for (int t=0; t<TLEN; t++){
    // ===== P0 (grpA): ch=[x_t|h]@W0 ; s0 = h + sig(C)*(tanh(H)-h) =====
    if (grpA){
      f32x4 ac0={0.f,0.f,0.f,0.f}, ac1={0.f,0.f,0.f,0.f};
      int gc = (m<8)?(cb8+m):(1024+cb8+m-8);
      const short* wB = W0T + (size_t)gc*2048 + (q<<3);   // x-part streamed (L2-hot)
      const float* x0 = x + ((size_t)row0*TLEN + t)*NH + (q<<3);
      const float* x1 = x + ((size_t)row1*TLEN + t)*NH + (q<<3);
      #pragma unroll 2
      for (int k0=0;k0<1024;k0+=32){
        bf16x8 b = *(const bf16x8*)(wB + k0);
        float4 u0=*(const float4*)(x0+k0), u1=*(const float4*)(x0+k0+4);
        float4 v0=*(const float4*)(x1+k0), v1=*(const float4*)(x1+k0+4);
        bf16x8 a0,a1;
        a0[0]=f2bf(u0.x); a0[1]=f2bf(u0.y); a0[2]=f2bf(u0.z); a0[3]=f2bf(u0.w);
        a0[4]=f2bf(u1.x); a0[5]=f2bf(u1.y); a0[6]=f2bf(u1.z); a0[7]=f2bf(u1.w);
        a1[0]=f2bf(v0.x); a1[1]=f2bf(v0.y); a1[2]=f2bf(v0.z); a1[3]=f2bf(v0.w);
        a1[4]=f2bf(v1.x); a1[5]=f2bf(v1.y); a1[6]=f2bf(v1.z); a1[7]=f2bf(v1.w);
        ac0 = __builtin_amdgcn_mfma_f32_16x16x32_bf16(a0, b, ac0, 0,0,0);
        ac1 = __builtin_amdgcn_mfma_f32_16x16x32_bf16(a1, b, ac1, 0,0,0);
      }
      const short* h0p = hB + (row0<<10) + (q<<3);
      const short* h1p = hB + (row1<<10) + (q<<3);
      #pragma unroll 4
      for (int k0=0;k0<1024;k0+=32){
        int j=(k0>>3)+q;
        bf16x8 b = *(const bf16x8*)(lds + SWZ(0,m,j));
        bf16x8 a0=*(const bf16x8*)(h0p+k0), a1=*(const bf16x8*)(h1p+k0);
        ac0 = __builtin_amdgcn_mfma_f32_16x16x32_bf16(a0, b, ac0, 0,0,0);
        ac1 = __builtin_amdgcn_mfma_f32_16x16x32_bf16(a1, b, ac1, 0,0,0);
      }
      #pragma unroll
      for (int rt=0; rt<2; rt++){
        f32x4 a = rt?ac1:ac0;
        #pragma unroll
        for (int i=0;i<4;i++){
          float H = __shfl(a[i], src8);
          if (m<8){
            int row=((rt?wv+4:wv)<<4)+(q<<2)+i;
            size_t o=((size_t)row<<10)+cb8+m;
            float hp=hF[o];
            float v=hp+sigf(a[i])*(tanhf(H)-hp);
            s0F[o]=v; s0B[o]=f2bf(v);
          }
        }
      }
    }
    target+=NWG; gsync(cnt,target);

    // ===== P1 (grpB): g0 sigmoid: s1 = s0 + sig(C)*(sig(H)-s0) =====
    if (!grpA){
      f32x4 ac0={0.f,0.f,0.f,0.f}, ac1={0.f,0.f,0.f,0.f};
      const short* a0p = s0B + (row0<<10) + (q<<3);
      const short* a1p = s0B + (row1<<10) + (q<<3);
      #pragma unroll 4
      for (int k0=0;k0<1024;k0+=32){
        int j=(k0>>3)+q;
        bf16x8 b=*(const bf16x8*)(lds + SWZ(0,m,j));
        ac0 = __builtin_amdgcn_mfma_f32_16x16x32_bf16(*(const bf16x8*)(a0p+k0), b, ac0, 0,0,0);
        ac1 = __builtin_amdgcn_mfma_f32_16x16x32_bf16(*(const bf16x8*)(a1p+k0), b, ac1, 0,0,0);
      }
      #pragma unroll
      for (int rt=0; rt<2; rt++){
        f32x4 a = rt?ac1:ac0;
        #pragma unroll
        for (int i=0;i<4;i++){
          float H = __shfl(a[i], src8);
          if (m<8){
            int row=((rt?wv+4:wv)<<4)+(q<<2)+i;
            size_t o=((size_t)row<<10)+cb8+m;
            float sp=s0F[o];
            float v=sp+sigf(a[i])*(sigf(H)-sp);
            s1F[o]=v; s1B[o]=f2bf(v);
          }
        }
      }
    }
    target+=NWG; gsync(cnt,target);

    // ===== P2 (all): g1 relu, g2 relu, g3 identity; A = s1 =====
    {
      f32x4 c10={0.f,0.f,0.f,0.f}, c11={0.f,0.f,0.f,0.f};
      f32x4 c20={0.f,0.f,0.f,0.f}, c21={0.f,0.f,0.f,0.f};
      f32x4 c30={0.f,0.f,0.f,0.f}, c31={0.f,0.f,0.f,0.f};
      const short* a0p = s1B + (row0<<10)+(q<<3);
      const short* a1p = s1B + (row1<<10)+(q<<3);
      const int c = m&7;
      #pragma unroll 2
      for (int k0=0;k0<1024;k0+=32){
        int j=(k0>>3)+q;
        bf16x8 b1=*(const bf16x8*)(lds + SWZ(32768,c,j));
        bf16x8 b2=*(const bf16x8*)(lds + SWZ(49152,c,j));
        bf16x8 b3=*(const bf16x8*)(lds + SWZ(65536,c,j));
        bf16x8 a0=*(const bf16x8*)(a0p+k0), a1=*(const bf16x8*)(a1p+k0);
        c10 = __builtin_amdgcn_mfma_f32_16x16x32_bf16(a0,b1,c10,0,0,0);
        c11 = __builtin_amdgcn_mfma_f32_16x16x32_bf16(a1,b1,c11,0,0,0);
        c20 = __builtin_amdgcn_mfma_f32_16x16x32_bf16(a0,b2,c20,0,0,0);
        c21 = __builtin_amdgcn_mfma_f32_16x16x32_bf16(a1,b2,c21,0,0,0);
        c30 = __builtin_amdgcn_mfma_f32_16x16x32_bf16(a0,b3,c30,0,0,0);
        c31 = __builtin_amdgcn_mfma_f32_16x16x32_bf16(a1,b3,c31,0,0,0);
      }
      #pragma unroll
      for (int rt=0; rt<2; rt++){
        f32x4 A1 = rt?c11:c10, A2 = rt?c21:c20, A3 = rt?c31:c30;
        #pragma unroll
        for (int i=0;i<4;i++){
          float H1=__shfl(A1[i],src4), H2=__shfl(A2[i],src4), H3=__shfl(A3[i],src4);
          if (m<4){
            int row=((rt?wv+4:wv)<<4)+(q<<2)+i;
            size_t o=((size_t)row<<10)+cb4+m;
            float sp=s1F[o];
            float v1=sp+sigf(A1[i])*(fmaxf(H1,0.f)-sp);
            float v2=sp+sigf(A2[i])*(fmaxf(H2,0.f)-sp);
            float v3=sp+sigf(A3[i])*(H3-sp);
            s2F[o]=v1; s2B[o]=f2bf(v1);
            s3F[o]=v2; s3B[o]=f2bf(v2);
            s4F[o]=v3;
          }
        }
      }
    }
    target+=NWG; gsync(cnt,target);

    // ===== P3: grpA: g4 tanh (A=s2) -> s5 ; grpB: g6 tanh (A=s3) -> s7 =====
    {
      const short* Ab = grpA ? s2B : s3B;
      const float* Sp = grpA ? s2F : s3F;
      f32x4 ac0={0.f,0.f,0.f,0.f}, ac1={0.f,0.f,0.f,0.f};
      const short* a0p = Ab + (row0<<10)+(q<<3);
      const short* a1p = Ab + (row1<<10)+(q<<3);
      #pragma unroll 4
      for (int k0=0;k0<1024;k0+=32){
        int j=(k0>>3)+q;
        bf16x8 b=*(const bf16x8*)(lds + SWZ(81920,m,j));
        ac0 = __builtin_amdgcn_mfma_f32_16x16x32_bf16(*(const bf16x8*)(a0p+k0), b, ac0, 0,0,0);
        ac1 = __builtin_amdgcn_mfma_f32_16x16x32_bf16(*(const bf16x8*)(a1p+k0), b, ac1, 0,0,0);
      }
      #pragma unroll
      for (int rt=0; rt<2; rt++){
        f32x4 a = rt?ac1:ac0;
        #pragma unroll
        for (int i=0;i<4;i++){
          float H = __shfl(a[i], src8);
          if (m<8){
            int row=((rt?wv+4:wv)<<4)+(q<<2)+i;
            size_t o=((size_t)row<<10)+cb8+m;
            float sp=Sp[o];
            float v=sp+sigf(a[i])*(tanhf(H)-sp);
            if (grpA){ s5F[o]=v; s5B[o]=f2bf(v); }
            else     { s7F[o]=v; }
          }
        }
      }
    }
    target+=NWG; gsync(cnt,target);

    // ===== P4 (all): g5 sigmoid + g7 relu (A=s5); s6,s8 inline; mean -> h,out =====
    {
      f32x4 c50={0.f,0.f,0.f,0.f}, c51={0.f,0.f,0.f,0.f};
      f32x4 c70={0.f,0.f,0.f,0.f}, c71={0.f,0.f,0.f,0.f};
      const short* a0p = s5B + (row0<<10)+(q<<3);
      const short* a1p = s5B + (row1<<10)+(q<<3);
      const int c = m&7;
      #pragma unroll 2
      for (int k0=0;k0<1024;k0+=32){
        int j=(k0>>3)+q;
        bf16x8 b5=*(const bf16x8*)(lds + SWZ(114688,c,j));
        bf16x8 b7=*(const bf16x8*)(lds + SWZ(131072,c,j));
        bf16x8 a0=*(const bf16x8*)(a0p+k0), a1=*(const bf16x8*)(a1p+k0);
        c50 = __builtin_amdgcn_mfma_f32_16x16x32_bf16(a0,b5,c50,0,0,0);
        c51 = __builtin_amdgcn_mfma_f32_16x16x32_bf16(a1,b5,c51,0,0,0);
        c70 = __builtin_amdgcn_mfma_f32_16x16x32_bf16(a0,b7,c70,0,0,0);
        c71 = __builtin_amdgcn_mfma_f32_16x16x32_bf16(a1,b7,c71,0,0,0);
      }
      #pragma unroll
      for (int rt=0; rt<2; rt++){
        f32x4 A5 = rt?c51:c50, A7 = rt?c71:c70;
        #pragma unroll
        for (int i=0;i<4;i++){
          float H5=__shfl(A5[i],src4), H7=__shfl(A7[i],src4);
          if (m<4){
            int row=((rt?wv+4:wv)<<4)+(q<<2)+i;
            size_t o=((size_t)row<<10)+cb4+m;
            float s5v=s5F[o];
            float s6v=s5v+sigf(A5[i])*(sigf(H5)-s5v);
            float s8v=s5v+sigf(A7[i])*(fmaxf(H7,0.f)-s5v);
            float mn=(s1F[o]+s2F[o]+s3F[o]+s4F[o]+s5v+s6v+s7F[o]+s8v)*0.125f;
            hF[o]=mn; hB[o]=f2bf(mn);
            out[((size_t)row*TLEN+t)*NH + cb4+m]=mn;
            if (t==TLEN-1) out[(size_t)BSZ*TLEN*NH + o]=mn;
          }
        }
      }
    }
    target+=NWG; gsync(cnt,target);
  }
}

extern "C" void kernel_launch(void* const* d_in, const int* in_sizes, int n_in,
                              void* d_out, int out_size, void* d_ws, size_t ws_size,
                              hipStream_t stream) {
  const float* x  = (const float*)d_in[0];   // (128, 256, 1024)
  const float* h0 = (const float*)d_in[1];   // (1, 128, 1024)
  const float* W0 = (const float*)d_in[2];   // (2048, 2048)
  const float* Ws = (const float*)d_in[3];   // (8, 1024, 2048)
  float* out = (float*)d_out;

  // ws: [0) W0T 8MB | [8M) WsT 32MB | [40M) F fp32 8 slots 4MB | [44M) Bb bf16 6 slots 1.5MB | [46M) counter
  char* wsb = (char*)d_ws;
  short* W0T = (short*)wsb;
  short* WsT = (short*)(wsb + (size_t)8*1024*1024);
  float* F   = (float*)(wsb + (size_t)40*1024*1024);
  short* Bb  = (short*)(wsb + (size_t)44*1024*1024);
  unsigned* cnt = (unsigned*)(wsb + (size_t)46*1024*1024);

  static int lds_set = 0;
  if (!lds_set){
    hipFuncSetAttribute((const void*)rnn_persistent,
                        hipFuncAttributeMaxDynamicSharedMemorySize, LDSB);
    lds_set = 1;
  }

  transpose_bf16<<<dim3(64,64,1),256,0,stream>>>(W0, W0T, 2048);
  transpose_bf16<<<dim3(64,32,8),256,0,stream>>>(Ws, WsT, 1024);
  init_h<<<dim3(512),256,0,stream>>>(h0, F + (size_t)7*SLOT, Bb + (size_t)5*SLOT);
  hipMemsetAsync(cnt, 0, 64, stream);

  rnn_persistent<<<dim3(NWG),256,LDSB,stream>>>(x, W0T, WsT, F, Bb, out, cnt);
}